// Round 11
// baseline (158.908 us; speedup 1.0000x reference)
//
#include <hip/hip_runtime.h>
#include <float.h>

// Problem constants (fixed by reference): B=32 L=1024 D=128 K=1024
#define NTOK 32768
#define DDIM 128
#define KCODES 1024
#define TT 128          // tokens per block -> 256 blocks = 1 block/CU (proven best)
#define NTHR 512        // 8 waves
#define KC 64           // codes per chunk (proven best)
#define NCHUNK (KCODES / KC)        // 16
#define CHUNK_BYTES (KC * 256 * 2)  // 32 KB: hi 16K | lo 16K, swizzled image
#define NBLK (NTOK / TT)            // 256

typedef __attribute__((ext_vector_type(8))) short short8v;   // 8 bf16 (4 VGPRs)
typedef __attribute__((ext_vector_type(4))) float f32x4;     // mfma accumulator

// Optimization barrier: prevents fma-contraction / reassociation across it,
// so we can replicate numpy's exact fp32 rounding sequence.
__device__ __forceinline__ float nofuse(float x) { asm volatile("" : "+v"(x)); return x; }

// bf16 round-to-nearest-even (finite data only)
__device__ __forceinline__ unsigned short bf16rne(float x) {
    unsigned int u = __float_as_uint(x);
    unsigned int r = u + 0x7FFFu + ((u >> 16) & 1u);
    return (unsigned short)(r >> 16);
}
__device__ __forceinline__ float bf16tof(unsigned short h) {
    return __uint_as_float(((unsigned int)h) << 16);
}

// split 8 floats into bf16 hi/lo packed words (2 bf16 per uint, d-ascending)
__device__ __forceinline__ void cvt8(const float* f, uint4& hw, uint4& lw) {
    unsigned int h[8], l[8];
    #pragma unroll
    for (int e = 0; e < 8; ++e) {
        unsigned short hh = bf16rne(f[e]);
        unsigned short ll = bf16rne(f[e] - bf16tof(hh));
        h[e] = hh; l[e] = ll;
    }
    hw = make_uint4(h[0] | (h[1] << 16), h[2] | (h[3] << 16),
                    h[4] | (h[5] << 16), h[6] | (h[7] << 16));
    lw = make_uint4(l[0] | (l[1] << 16), l[2] | (l[3] << 16),
                    l[4] | (l[5] << 16), l[6] | (l[7] << 16));
}

__device__ __forceinline__ short8v as_s8(uint4 v) { return __builtin_bit_cast(short8v, v); }

// ---------------- pack codebook -> swizzled bf16 hi/lo chunk images + norms ----------------
// Image for chunk c (64 codes): 32 KB = [hi: row r in 0..63, 256 B,
// col byte = (d8*16)^((r&7)*16)] then [lo: same layout at +16384].
// One thread per 8-element unit (16384 threads) -> packing fully parallel.
__global__ __launch_bounds__(256)
void pack_cb(const float* __restrict__ cb, float* __restrict__ cnorm,
             char* __restrict__ cbS, int* __restrict__ done_ctr) {
    const int tid = threadIdx.x;
    if (blockIdx.x == 0 && tid == 0) *done_ctr = 0;   // reset each replay
    const int u   = blockIdx.x * 256 + tid;   // 64 blocks x 256 = 16384 units
    const int row = u >> 4;                   // 0..1023
    const int d8  = u & 15;
    const float* p = cb + (size_t)row * DDIM;
    // ---- pack this 8-elem unit ----
    {
        float4 a = *(const float4*)(p + d8 * 8), c = *(const float4*)(p + d8 * 8 + 4);
        float f[8] = {a.x, a.y, a.z, a.w, c.x, c.y, c.z, c.w};
        uint4 hw, lw;
        cvt8(f, hw, lw);
        char* base = cbS + (size_t)(row >> 6) * CHUNK_BYTES + (size_t)(row & 63) * 256;
        int col = (d8 << 4) ^ ((row & 7) << 4);
        *(uint4*)(base + col) = hw;
        *(uint4*)(base + 16384 + col) = lw;
    }
    // ---- norm (d8==0 lanes): numpy pairwise_sum order (squares pre-rounded) ----
    if (d8 == 0) {
        float r[8];
        {
            float4 a = *(const float4*)p, c = *(const float4*)(p + 4);
            float v[8] = {a.x, a.y, a.z, a.w, c.x, c.y, c.z, c.w};
            #pragma unroll
            for (int j = 0; j < 8; ++j) r[j] = nofuse(v[j] * v[j]);
        }
        #pragma unroll
        for (int i = 8; i < DDIM; i += 8) {
            float4 a = *(const float4*)(p + i), c = *(const float4*)(p + i + 4);
            float v[8] = {a.x, a.y, a.z, a.w, c.x, c.y, c.z, c.w};
            #pragma unroll
            for (int j = 0; j < 8; ++j) r[j] = nofuse(r[j] + nofuse(v[j] * v[j]));
        }
        float s01 = nofuse(r[0] + r[1]), s23 = nofuse(r[2] + r[3]);
        float s45 = nofuse(r[4] + r[5]), s67 = nofuse(r[6] + r[7]);
        cnorm[row] = nofuse(nofuse(s01 + s23) + nofuse(s45 + s67));
    }
}

// ---------------- distances (split-bf16 MFMA) + argmin + gather + loss (fused) ----------------
// VERBATIM the 47us R5 structure: KC=64, double buffer, 2 barriers/chunk,
// counted vmcnt(4), lgkmcnt(0)+sched_barrier pin before the MFMA cluster,
// 32tok x 32code wave tile. Only additions: tail-block loss reduce at the end.
__global__ __launch_bounds__(NTHR, 2)
void dist_argmin(const float* __restrict__ z, const float* __restrict__ cb,
                 const float* __restrict__ cnorm, const char* __restrict__ cbS,
                 float* __restrict__ zq, float* __restrict__ idxf_out,
                 float* __restrict__ partials, int* __restrict__ done_ctr,
                 float* __restrict__ out_loss) {
    __shared__ __align__(16) char buf[2 * CHUNK_BYTES];   // 64 KB double buffer
    __shared__ float zn_s[TT];
    __shared__ float cn_s[KCODES];
    __shared__ float red_v[TT * 2];
    __shared__ int   red_i[TT * 2];
    __shared__ int   bidx[TT];
    __shared__ float smf[8];
    __shared__ int   lastflag;

    const int tid  = threadIdx.x;
    const int lane = tid & 63;
    const int wave = tid >> 6;     // 0..7
    const int wy   = wave & 3;     // token group: 32 tokens
    const int wx   = wave >> 2;    // code group: 32 codes per 64-code chunk
    const int l15  = lane & 15;
    const int l4   = lane >> 4;    // 0..3
    const int t0   = blockIdx.x * TT;

    // DMA one chunk: identity copy of the 32 KB image (swizzle pre-baked in source).
    auto stage = [&](int slot, int chunk) {
        const char* g = cbS + (size_t)chunk * CHUNK_BYTES + wave * 4096 + (lane << 4);
        char* ldst = buf + slot * CHUNK_BYTES + wave * 4096;
        #pragma unroll
        for (int j = 0; j < 4; ++j)
            __builtin_amdgcn_global_load_lds(
                (const __attribute__((address_space(1))) unsigned int*)(g + j * 1024),
                (__attribute__((address_space(3))) unsigned int*)(ldst + j * 1024),
                16, 0, 0);
    };

    // ---- A fragments: global -> cvt -> registers (32 tokens/wave: tf=0..1) ----
    // mfma A layout: lane holds A[m = lane&15][k = (lane>>4)*8 + j]
    short8v Ah[2][4], Al[2][4];
    #pragma unroll
    for (int tf = 0; tf < 2; ++tf) {
        int row = t0 + wy * 32 + tf * 16 + l15;
        const float* p = z + (size_t)row * DDIM;
        #pragma unroll
        for (int ks = 0; ks < 4; ++ks) {
            float4 a = *(const float4*)(p + ks * 32 + l4 * 8);
            float4 c = *(const float4*)(p + ks * 32 + l4 * 8 + 4);
            float f[8] = {a.x, a.y, a.z, a.w, c.x, c.y, c.z, c.w};
            uint4 hw, lw;
            cvt8(f, hw, lw);
            Ah[tf][ks] = as_s8(hw);
            Al[tf][ks] = as_s8(lw);
        }
    }

    // ---- stage chunk 0 (DMA in flight over znorm/cnorm prologue) ----
    stage(0, 0);

    // ---- cnorm -> LDS (avoids in-loop global loads that would drain vmcnt) ----
    cn_s[tid]       = cnorm[tid];
    cn_s[tid + 512] = cnorm[tid + 512];

    // ---- znorm: exact numpy pairwise sequence from global fp32 ----
    if (tid < TT) {
        const float* p = z + (size_t)(t0 + tid) * DDIM;
        float r[8];
        {
            float4 a = *(const float4*)p, c = *(const float4*)(p + 4);
            float v[8] = {a.x, a.y, a.z, a.w, c.x, c.y, c.z, c.w};
            #pragma unroll
            for (int j = 0; j < 8; ++j) r[j] = nofuse(v[j] * v[j]);
        }
        #pragma unroll
        for (int i = 8; i < DDIM; i += 8) {
            float4 a = *(const float4*)(p + i), c = *(const float4*)(p + i + 4);
            float v[8] = {a.x, a.y, a.z, a.w, c.x, c.y, c.z, c.w};
            #pragma unroll
            for (int j = 0; j < 8; ++j) r[j] = nofuse(r[j] + nofuse(v[j] * v[j]));
        }
        float s01 = nofuse(r[0] + r[1]), s23 = nofuse(r[2] + r[3]);
        float s45 = nofuse(r[4] + r[5]), s67 = nofuse(r[6] + r[7]);
        zn_s[tid] = nofuse(nofuse(s01 + s23) + nofuse(s45 + s67));
    }
    __syncthreads();   // zn_s/cn_s ready; full drain -> chunk 0 resident too

    float znr[8];
    #pragma unroll
    for (int tf = 0; tf < 2; ++tf)
        #pragma unroll
        for (int rg = 0; rg < 4; ++rg)
            znr[tf * 4 + rg] = zn_s[wy * 32 + tf * 16 + l4 * 4 + rg];

    float minv[8]; int mini[8];
    #pragma unroll
    for (int i = 0; i < 8; ++i) { minv[i] = FLT_MAX; mini[i] = 0; }

    auto compute = [&](int slot, int it) {
        const char* bb = buf + slot * CHUNK_BYTES;
        short8v Bh[2][4], Bl[2][4];
        #pragma unroll
        for (int cf = 0; cf < 2; ++cf) {
            int r = wx * 32 + cf * 16 + l15;
            int swz = (r & 7) << 4;
            #pragma unroll
            for (int ks = 0; ks < 4; ++ks) {
                int off = r * 256 + ((((ks * 4 + l4) << 4)) ^ swz);
                Bh[cf][ks] = *(const short8v*)(bb + off);
                Bl[cf][ks] = *(const short8v*)(bb + 16384 + off);
            }
        }
        asm volatile("s_waitcnt lgkmcnt(0)" ::: "memory");
        __builtin_amdgcn_sched_barrier(0);   // pin MFMA cluster after the wait (47us config)

        f32x4 acc[2][2];
        #pragma unroll
        for (int tf = 0; tf < 2; ++tf)
            #pragma unroll
            for (int cf = 0; cf < 2; ++cf)
                acc[tf][cf] = (f32x4){0.f, 0.f, 0.f, 0.f};
        // identical chain order to all passing rounds (ks ascending; hh,hl,lh)
        #pragma unroll
        for (int ks = 0; ks < 4; ++ks)
            #pragma unroll
            for (int tf = 0; tf < 2; ++tf)
                #pragma unroll
                for (int cf = 0; cf < 2; ++cf) {
                    acc[tf][cf] = __builtin_amdgcn_mfma_f32_16x16x32_bf16(Ah[tf][ks], Bh[cf][ks], acc[tf][cf], 0, 0, 0);
                    acc[tf][cf] = __builtin_amdgcn_mfma_f32_16x16x32_bf16(Ah[tf][ks], Bl[cf][ks], acc[tf][cf], 0, 0, 0);
                    acc[tf][cf] = __builtin_amdgcn_mfma_f32_16x16x32_bf16(Al[tf][ks], Bh[cf][ks], acc[tf][cf], 0, 0, 0);
                }
        // epilogue: C/D layout col=lane&15 (code), row=(lane>>4)*4+reg (token)
        #pragma unroll
        for (int cf = 0; cf < 2; ++cf) {
            int kk = it * KC + wx * 32 + cf * 16 + l15;   // ascends within thread
            float cn = cn_s[kk];                           // LDS, no vmcnt impact
            #pragma unroll
            for (int tf = 0; tf < 2; ++tf)
                #pragma unroll
                for (int rg = 0; rg < 4; ++rg) {
                    // s = fl(zn + cn); dist = fl(s - 2*acc); 2*acc exact (pow2)
                    float s = nofuse(znr[tf * 4 + rg] + cn);
                    float dist = fmaf(-2.0f, acc[tf][cf][rg], s);
                    int ii = tf * 4 + rg;
                    if (dist < minv[ii]) { minv[ii] = dist; mini[ii] = kk; }
                }
        }
    };

    // ---- pipelined chunk loop: counted vmcnt, raw barriers (47us config) ----
    int cur = 0;
    #pragma unroll 1
    for (int t = 0; t < NCHUNK - 1; ++t) {
        stage(cur ^ 1, t + 1);                              // DMA next; <=8 in flight
        asm volatile("s_waitcnt vmcnt(4)" ::: "memory");    // chunk t landed (mine)
        __builtin_amdgcn_s_barrier();                       // ... and everyone's
        compute(cur, t);
        asm volatile("s_waitcnt lgkmcnt(0)" ::: "memory");  // my LDS reads drained
        __builtin_amdgcn_s_barrier();                       // buf[cur] safe to overwrite next iter
        cur ^= 1;
    }
    asm volatile("s_waitcnt vmcnt(0)" ::: "memory");
    __builtin_amdgcn_s_barrier();
    compute(cur, NCHUNK - 1);

    // ---- argmin reduce: butterfly over 16 code-lanes, then across 2 wx waves ----
    #pragma unroll
    for (int i = 0; i < 8; ++i) {
        float bv = minv[i]; int bi = mini[i];
        #pragma unroll
        for (int off = 1; off < 16; off <<= 1) {   // xor<16 stays in 16-lane group
            float ov = __shfl_xor(bv, off);
            int   oi = __shfl_xor(bi, off);
            if (ov < bv || (ov == bv && oi < bi)) { bv = ov; bi = oi; }
        }
        if (l15 == 0) {
            int tok = wy * 32 + (i >> 2) * 16 + l4 * 4 + (i & 3);
            red_v[tok * 2 + wx] = bv;
            red_i[tok * 2 + wx] = bi;
        }
    }
    __syncthreads();
    if (tid < TT) {
        float bv = red_v[tid * 2]; int bi = red_i[tid * 2];
        float v1 = red_v[tid * 2 + 1]; int i1 = red_i[tid * 2 + 1];
        if (v1 < bv || (v1 == bv && i1 < bi)) { bv = v1; bi = i1; }
        bidx[tid] = bi;
        idxf_out[t0 + tid] = (float)bi;
    }
    __syncthreads();

    // ---- fused gather z_q + loss partial (fp32 exact copies from cb) ----
    float s = 0.0f;
    #pragma unroll
    for (int ft = 0; ft < 8; ++ft) {
        int g = ft * NTHR + tid;
        int t = g >> 5;          // 0..127 (32 lanes share t -> LDS broadcast)
        int d4 = g & 31;
        int k = bidx[t];
        float4 q4 = *(const float4*)(cb + (size_t)k * DDIM + 4 * d4);
        float4 z4 = *(const float4*)(z + (size_t)(t0 + t) * DDIM + 4 * d4);
        *(float4*)(zq + (size_t)(t0 + t) * DDIM + 4 * d4) = q4;
        float dx = q4.x - z4.x, dy = q4.y - z4.y, dz = q4.z - z4.z, dw = q4.w - z4.w;
        s += dx * dx + dy * dy + dz * dz + dw * dw;
    }
    #pragma unroll
    for (int off = 32; off > 0; off >>= 1) s += __shfl_down(s, off);
    if ((tid & 63) == 0) smf[tid >> 6] = s;
    __syncthreads();
    if (tid == 0) partials[blockIdx.x] = smf[0] + smf[1] + smf[2] + smf[3]
                                       + smf[4] + smf[5] + smf[6] + smf[7];

    // ---- tail block: deterministic final loss reduce (kills a launch) ----
    __threadfence();
    if (tid == 0) lastflag = (atomicAdd(done_ctr, 1) == NBLK - 1);
    __syncthreads();
    if (lastflag) {
        __threadfence();   // acquire: see all blocks' partials
        double d = (tid < NBLK) ? (double)partials[tid] : 0.0;
        #pragma unroll
        for (int off = 32; off > 0; off >>= 1) d += __shfl_down(d, off);
        __shared__ double smd[8];
        if ((tid & 63) == 0) smd[tid >> 6] = d;
        __syncthreads();
        if (tid == 0) {
            double tot = 0.0;
            #pragma unroll
            for (int w = 0; w < 8; ++w) tot += smd[w];
            // vq_loss = (1 + 0.25) * mean((q - z)^2)
            out_loss[0] = (float)(tot * 1.25 / (double)((size_t)NTOK * DDIM));
        }
    }
}

extern "C" void kernel_launch(void* const* d_in, const int* in_sizes, int n_in,
                              void* d_out, int out_size, void* d_ws, size_t ws_size,
                              hipStream_t stream) {
    const float* z  = (const float*)d_in[0];   // [32768,128]
    const float* cb = (const float*)d_in[1];   // [1024,128]
    float* out = (float*)d_out;
    float* zq   = out;                         // 4194304
    float* loss = out + (size_t)NTOK * DDIM;   // 1
    float* idxf = loss + 1;                    // 32768 (indices as float)

    float* cnorm    = (float*)d_ws;                  // 1024 f (4 KB)
    float* partials = cnorm + KCODES;                // 256 f  (1 KB)
    int*   done_ctr = (int*)(partials + NBLK);       // 4 ints (pad to 16 B)
    char*  cbS      = (char*)(done_ctr + 4);         // 16 x 32 KB swizzled images (512 KB)

    pack_cb<<<64, 256, 0, stream>>>(cb, cnorm, cbS, done_ctr);
    dist_argmin<<<NBLK, NTHR, 0, stream>>>(z, cb, cnorm, cbS, zq, idxf,
                                           partials, done_ctr, loss);
}

// Round 12
// 111.935 us; speedup vs baseline: 1.4196x; 1.4196x over previous
//
#include <hip/hip_runtime.h>
#include <float.h>

// Problem constants (fixed by reference): B=32 L=1024 D=128 K=1024
#define NTOK 32768
#define DDIM 128
#define KCODES 1024
#define TT 128          // tokens per block -> 256 blocks = 1 block/CU (proven best)
#define NTHR 512        // 8 waves
#define KC 64           // codes per chunk (proven best)
#define NCHUNK (KCODES / KC)        // 16
#define CHUNK_BYTES (KC * 256 * 2)  // 32 KB: hi 16K | lo 16K, swizzled image
#define NBLK (NTOK / TT)            // 256

typedef __attribute__((ext_vector_type(8))) short short8v;   // 8 bf16 (4 VGPRs)
typedef __attribute__((ext_vector_type(4))) float f32x4;     // mfma accumulator

// Optimization barrier: prevents fma-contraction / reassociation across it,
// so we can replicate numpy's exact fp32 rounding sequence.
__device__ __forceinline__ float nofuse(float x) { asm volatile("" : "+v"(x)); return x; }

// bf16 round-to-nearest-even (finite data only)
__device__ __forceinline__ unsigned short bf16rne(float x) {
    unsigned int u = __float_as_uint(x);
    unsigned int r = u + 0x7FFFu + ((u >> 16) & 1u);
    return (unsigned short)(r >> 16);
}
__device__ __forceinline__ float bf16tof(unsigned short h) {
    return __uint_as_float(((unsigned int)h) << 16);
}

// split 8 floats into bf16 hi/lo packed words (2 bf16 per uint, d-ascending)
__device__ __forceinline__ void cvt8(const float* f, uint4& hw, uint4& lw) {
    unsigned int h[8], l[8];
    #pragma unroll
    for (int e = 0; e < 8; ++e) {
        unsigned short hh = bf16rne(f[e]);
        unsigned short ll = bf16rne(f[e] - bf16tof(hh));
        h[e] = hh; l[e] = ll;
    }
    hw = make_uint4(h[0] | (h[1] << 16), h[2] | (h[3] << 16),
                    h[4] | (h[5] << 16), h[6] | (h[7] << 16));
    lw = make_uint4(l[0] | (l[1] << 16), l[2] | (l[3] << 16),
                    l[4] | (l[5] << 16), l[6] | (l[7] << 16));
}

__device__ __forceinline__ short8v as_s8(uint4 v) { return __builtin_bit_cast(short8v, v); }

// ---------------- pack codebook -> swizzled bf16 hi/lo chunk images + norms ----------------
// Image for chunk c (64 codes): 32 KB = [hi: row r in 0..63, 256 B,
// col byte = (d8*16)^((r&7)*16)] then [lo: same layout at +16384].
// One thread per 8-element unit (16384 threads) -> packing fully parallel.
// NO atomics/fences anywhere (R11 isolation: the tail-reduce dispatch was the
// only unexplained delta vs the 47us R5 config).
__global__ __launch_bounds__(256)
void pack_cb(const float* __restrict__ cb, float* __restrict__ cnorm,
             char* __restrict__ cbS) {
    const int tid = threadIdx.x;
    const int u   = blockIdx.x * 256 + tid;   // 64 blocks x 256 = 16384 units
    const int row = u >> 4;                   // 0..1023
    const int d8  = u & 15;
    const float* p = cb + (size_t)row * DDIM;
    // ---- pack this 8-elem unit ----
    {
        float4 a = *(const float4*)(p + d8 * 8), c = *(const float4*)(p + d8 * 8 + 4);
        float f[8] = {a.x, a.y, a.z, a.w, c.x, c.y, c.z, c.w};
        uint4 hw, lw;
        cvt8(f, hw, lw);
        char* base = cbS + (size_t)(row >> 6) * CHUNK_BYTES + (size_t)(row & 63) * 256;
        int col = (d8 << 4) ^ ((row & 7) << 4);
        *(uint4*)(base + col) = hw;
        *(uint4*)(base + 16384 + col) = lw;
    }
    // ---- norm (d8==0 lanes): numpy pairwise_sum order (squares pre-rounded) ----
    if (d8 == 0) {
        float r[8];
        {
            float4 a = *(const float4*)p, c = *(const float4*)(p + 4);
            float v[8] = {a.x, a.y, a.z, a.w, c.x, c.y, c.z, c.w};
            #pragma unroll
            for (int j = 0; j < 8; ++j) r[j] = nofuse(v[j] * v[j]);
        }
        #pragma unroll
        for (int i = 8; i < DDIM; i += 8) {
            float4 a = *(const float4*)(p + i), c = *(const float4*)(p + i + 4);
            float v[8] = {a.x, a.y, a.z, a.w, c.x, c.y, c.z, c.w};
            #pragma unroll
            for (int j = 0; j < 8; ++j) r[j] = nofuse(r[j] + nofuse(v[j] * v[j]));
        }
        float s01 = nofuse(r[0] + r[1]), s23 = nofuse(r[2] + r[3]);
        float s45 = nofuse(r[4] + r[5]), s67 = nofuse(r[6] + r[7]);
        cnorm[row] = nofuse(nofuse(s01 + s23) + nofuse(s45 + s67));
    }
}

// ---------------- distances (split-bf16 MFMA) + argmin + gather + loss partials ----------------
// BYTE-FOR-BYTE the 47us R5 kernel: KC=64, double buffer, 2 barriers/chunk,
// counted vmcnt(4), lgkmcnt(0)+sched_barrier pin, 32tok x 32code wave tile,
// no atomics, no fences, partials written per block; loss_final reduces.
__global__ __launch_bounds__(NTHR, 2)
void dist_argmin(const float* __restrict__ z, const float* __restrict__ cb,
                 const float* __restrict__ cnorm, const char* __restrict__ cbS,
                 float* __restrict__ zq, float* __restrict__ idxf_out,
                 float* __restrict__ partials) {
    __shared__ __align__(16) char buf[2 * CHUNK_BYTES];   // 64 KB double buffer
    __shared__ float zn_s[TT];
    __shared__ float cn_s[KCODES];
    __shared__ float red_v[TT * 2];
    __shared__ int   red_i[TT * 2];
    __shared__ int   bidx[TT];
    __shared__ float smf[8];

    const int tid  = threadIdx.x;
    const int lane = tid & 63;
    const int wave = tid >> 6;     // 0..7
    const int wy   = wave & 3;     // token group: 32 tokens
    const int wx   = wave >> 2;    // code group: 32 codes per 64-code chunk
    const int l15  = lane & 15;
    const int l4   = lane >> 4;    // 0..3
    const int t0   = blockIdx.x * TT;

    // DMA one chunk: identity copy of the 32 KB image (swizzle pre-baked in source).
    auto stage = [&](int slot, int chunk) {
        const char* g = cbS + (size_t)chunk * CHUNK_BYTES + wave * 4096 + (lane << 4);
        char* ldst = buf + slot * CHUNK_BYTES + wave * 4096;
        #pragma unroll
        for (int j = 0; j < 4; ++j)
            __builtin_amdgcn_global_load_lds(
                (const __attribute__((address_space(1))) unsigned int*)(g + j * 1024),
                (__attribute__((address_space(3))) unsigned int*)(ldst + j * 1024),
                16, 0, 0);
    };

    // ---- A fragments: global -> cvt -> registers (32 tokens/wave: tf=0..1) ----
    // mfma A layout: lane holds A[m = lane&15][k = (lane>>4)*8 + j]
    short8v Ah[2][4], Al[2][4];
    #pragma unroll
    for (int tf = 0; tf < 2; ++tf) {
        int row = t0 + wy * 32 + tf * 16 + l15;
        const float* p = z + (size_t)row * DDIM;
        #pragma unroll
        for (int ks = 0; ks < 4; ++ks) {
            float4 a = *(const float4*)(p + ks * 32 + l4 * 8);
            float4 c = *(const float4*)(p + ks * 32 + l4 * 8 + 4);
            float f[8] = {a.x, a.y, a.z, a.w, c.x, c.y, c.z, c.w};
            uint4 hw, lw;
            cvt8(f, hw, lw);
            Ah[tf][ks] = as_s8(hw);
            Al[tf][ks] = as_s8(lw);
        }
    }

    // ---- stage chunk 0 (DMA in flight over znorm/cnorm prologue) ----
    stage(0, 0);

    // ---- cnorm -> LDS (avoids in-loop global loads that would drain vmcnt) ----
    cn_s[tid]       = cnorm[tid];
    cn_s[tid + 512] = cnorm[tid + 512];

    // ---- znorm: exact numpy pairwise sequence from global fp32 ----
    if (tid < TT) {
        const float* p = z + (size_t)(t0 + tid) * DDIM;
        float r[8];
        {
            float4 a = *(const float4*)p, c = *(const float4*)(p + 4);
            float v[8] = {a.x, a.y, a.z, a.w, c.x, c.y, c.z, c.w};
            #pragma unroll
            for (int j = 0; j < 8; ++j) r[j] = nofuse(v[j] * v[j]);
        }
        #pragma unroll
        for (int i = 8; i < DDIM; i += 8) {
            float4 a = *(const float4*)(p + i), c = *(const float4*)(p + i + 4);
            float v[8] = {a.x, a.y, a.z, a.w, c.x, c.y, c.z, c.w};
            #pragma unroll
            for (int j = 0; j < 8; ++j) r[j] = nofuse(r[j] + nofuse(v[j] * v[j]));
        }
        float s01 = nofuse(r[0] + r[1]), s23 = nofuse(r[2] + r[3]);
        float s45 = nofuse(r[4] + r[5]), s67 = nofuse(r[6] + r[7]);
        zn_s[tid] = nofuse(nofuse(s01 + s23) + nofuse(s45 + s67));
    }
    __syncthreads();   // zn_s/cn_s ready; full drain -> chunk 0 resident too

    float znr[8];
    #pragma unroll
    for (int tf = 0; tf < 2; ++tf)
        #pragma unroll
        for (int rg = 0; rg < 4; ++rg)
            znr[tf * 4 + rg] = zn_s[wy * 32 + tf * 16 + l4 * 4 + rg];

    float minv[8]; int mini[8];
    #pragma unroll
    for (int i = 0; i < 8; ++i) { minv[i] = FLT_MAX; mini[i] = 0; }

    auto compute = [&](int slot, int it) {
        const char* bb = buf + slot * CHUNK_BYTES;
        short8v Bh[2][4], Bl[2][4];
        #pragma unroll
        for (int cf = 0; cf < 2; ++cf) {
            int r = wx * 32 + cf * 16 + l15;
            int swz = (r & 7) << 4;
            #pragma unroll
            for (int ks = 0; ks < 4; ++ks) {
                int off = r * 256 + ((((ks * 4 + l4) << 4)) ^ swz);
                Bh[cf][ks] = *(const short8v*)(bb + off);
                Bl[cf][ks] = *(const short8v*)(bb + 16384 + off);
            }
        }
        asm volatile("s_waitcnt lgkmcnt(0)" ::: "memory");
        __builtin_amdgcn_sched_barrier(0);   // pin MFMA cluster after the wait (47us config)

        f32x4 acc[2][2];
        #pragma unroll
        for (int tf = 0; tf < 2; ++tf)
            #pragma unroll
            for (int cf = 0; cf < 2; ++cf)
                acc[tf][cf] = (f32x4){0.f, 0.f, 0.f, 0.f};
        // identical chain order to all passing rounds (ks ascending; hh,hl,lh)
        #pragma unroll
        for (int ks = 0; ks < 4; ++ks)
            #pragma unroll
            for (int tf = 0; tf < 2; ++tf)
                #pragma unroll
                for (int cf = 0; cf < 2; ++cf) {
                    acc[tf][cf] = __builtin_amdgcn_mfma_f32_16x16x32_bf16(Ah[tf][ks], Bh[cf][ks], acc[tf][cf], 0, 0, 0);
                    acc[tf][cf] = __builtin_amdgcn_mfma_f32_16x16x32_bf16(Ah[tf][ks], Bl[cf][ks], acc[tf][cf], 0, 0, 0);
                    acc[tf][cf] = __builtin_amdgcn_mfma_f32_16x16x32_bf16(Al[tf][ks], Bh[cf][ks], acc[tf][cf], 0, 0, 0);
                }
        // epilogue: C/D layout col=lane&15 (code), row=(lane>>4)*4+reg (token)
        #pragma unroll
        for (int cf = 0; cf < 2; ++cf) {
            int kk = it * KC + wx * 32 + cf * 16 + l15;   // ascends within thread
            float cn = cn_s[kk];                           // LDS, no vmcnt impact
            #pragma unroll
            for (int tf = 0; tf < 2; ++tf)
                #pragma unroll
                for (int rg = 0; rg < 4; ++rg) {
                    // s = fl(zn + cn); dist = fl(s - 2*acc); 2*acc exact (pow2)
                    float s = nofuse(znr[tf * 4 + rg] + cn);
                    float dist = fmaf(-2.0f, acc[tf][cf][rg], s);
                    int ii = tf * 4 + rg;
                    if (dist < minv[ii]) { minv[ii] = dist; mini[ii] = kk; }
                }
        }
    };

    // ---- pipelined chunk loop: counted vmcnt, raw barriers (47us config) ----
    int cur = 0;
    #pragma unroll 1
    for (int t = 0; t < NCHUNK - 1; ++t) {
        stage(cur ^ 1, t + 1);                              // DMA next; <=8 in flight
        asm volatile("s_waitcnt vmcnt(4)" ::: "memory");    // chunk t landed (mine)
        __builtin_amdgcn_s_barrier();                       // ... and everyone's
        compute(cur, t);
        asm volatile("s_waitcnt lgkmcnt(0)" ::: "memory");  // my LDS reads drained
        __builtin_amdgcn_s_barrier();                       // buf[cur] safe to overwrite next iter
        cur ^= 1;
    }
    asm volatile("s_waitcnt vmcnt(0)" ::: "memory");
    __builtin_amdgcn_s_barrier();
    compute(cur, NCHUNK - 1);

    // ---- argmin reduce: butterfly over 16 code-lanes, then across 2 wx waves ----
    #pragma unroll
    for (int i = 0; i < 8; ++i) {
        float bv = minv[i]; int bi = mini[i];
        #pragma unroll
        for (int off = 1; off < 16; off <<= 1) {   // xor<16 stays in 16-lane group
            float ov = __shfl_xor(bv, off);
            int   oi = __shfl_xor(bi, off);
            if (ov < bv || (ov == bv && oi < bi)) { bv = ov; bi = oi; }
        }
        if (l15 == 0) {
            int tok = wy * 32 + (i >> 2) * 16 + l4 * 4 + (i & 3);
            red_v[tok * 2 + wx] = bv;
            red_i[tok * 2 + wx] = bi;
        }
    }
    __syncthreads();
    if (tid < TT) {
        float bv = red_v[tid * 2]; int bi = red_i[tid * 2];
        float v1 = red_v[tid * 2 + 1]; int i1 = red_i[tid * 2 + 1];
        if (v1 < bv || (v1 == bv && i1 < bi)) { bv = v1; bi = i1; }
        bidx[tid] = bi;
        idxf_out[t0 + tid] = (float)bi;
    }
    __syncthreads();

    // ---- fused gather z_q + loss partial (fp32 exact copies from cb) ----
    float s = 0.0f;
    #pragma unroll
    for (int ft = 0; ft < 8; ++ft) {
        int g = ft * NTHR + tid;
        int t = g >> 5;          // 0..127 (32 lanes share t -> LDS broadcast)
        int d4 = g & 31;
        int k = bidx[t];
        float4 q4 = *(const float4*)(cb + (size_t)k * DDIM + 4 * d4);
        float4 z4 = *(const float4*)(z + (size_t)(t0 + t) * DDIM + 4 * d4);
        *(float4*)(zq + (size_t)(t0 + t) * DDIM + 4 * d4) = q4;
        float dx = q4.x - z4.x, dy = q4.y - z4.y, dz = q4.z - z4.z, dw = q4.w - z4.w;
        s += dx * dx + dy * dy + dz * dz + dw * dw;
    }
    #pragma unroll
    for (int off = 32; off > 0; off >>= 1) s += __shfl_down(s, off);
    if ((tid & 63) == 0) smf[tid >> 6] = s;
    __syncthreads();
    if (tid == 0) {
        float tot = 0.0f;
        #pragma unroll
        for (int w = 0; w < 8; ++w) tot += smf[w];
        partials[blockIdx.x] = tot;
    }
}

// ---------------- final loss reduce ----------------
__global__ void loss_final(const float* __restrict__ partials, float* __restrict__ out_loss) {
    double s = 0.0;
    for (int i = threadIdx.x; i < NBLK; i += 256) s += (double)partials[i];
    #pragma unroll
    for (int off = 32; off > 0; off >>= 1) s += __shfl_down(s, off);
    __shared__ double sm[4];
    int lane = threadIdx.x & 63, wv = threadIdx.x >> 6;
    if (lane == 0) sm[wv] = s;
    __syncthreads();
    if (threadIdx.x == 0) {
        double tot = sm[0] + sm[1] + sm[2] + sm[3];
        // vq_loss = (1 + 0.25) * mean((q - z)^2)
        out_loss[0] = (float)(tot * 1.25 / (double)((size_t)NTOK * DDIM));
    }
}

extern "C" void kernel_launch(void* const* d_in, const int* in_sizes, int n_in,
                              void* d_out, int out_size, void* d_ws, size_t ws_size,
                              hipStream_t stream) {
    const float* z  = (const float*)d_in[0];   // [32768,128]
    const float* cb = (const float*)d_in[1];   // [1024,128]
    float* out = (float*)d_out;
    float* zq   = out;                         // 4194304
    float* loss = out + (size_t)NTOK * DDIM;   // 1
    float* idxf = loss + 1;                    // 32768 (indices as float)

    // EXACT R5 workspace layout (cbS 64B-aligned at byte 5120)
    float* cnorm    = (float*)d_ws;                  // 1024 f (4 KB)
    float* partials = cnorm + KCODES;                // 256 f  (1 KB)
    char*  cbS      = (char*)(partials + 256);       // 16 x 32 KB swizzled images (512 KB)

    pack_cb<<<64, 256, 0, stream>>>(cb, cnorm, cbS);
    dist_argmin<<<NBLK, NTHR, 0, stream>>>(z, cb, cnorm, cbS, zq, idxf, partials);
    loss_final<<<1, 256, 0, stream>>>(partials, loss);
}